// Round 11
// baseline (239.590 us; speedup 1.0000x reference)
//
#include <hip/hip_runtime.h>

// VQ-VAE quantize: z [32,64,64,64] NCHW fp32, codebook [512,64] fp32.
// out = quantized (8388608 fp32, NCHW) ++ loss scalar. N=131072, D=64, K=512.
//
// R11: (1) cb tiles staged with __builtin_amdgcn_global_load_lds (16B) into a
// double-buffered LDS region, issued right AFTER each barrier so loads land
// under the next compute phase (m97 pattern) -- kills R10's register-prefetch
// spill (+15.7MB scratch WRITE) and the WRITE_TILE VALU; (2) LDS union: zT is
// dead after A-fragment build, its 32KB is reused for the cb dbuf -> ~41.5KB
// LDS -> 3 blocks/CU (R10 ran ~1 resident, 80% stall); fallback/epilogue
// re-read z from global (L2-warm); (3) CROW=76 -> 38-dword row stride ->
// uniform 2-way LDS aliasing (free), tile = exactly 19KB = 19 wave-calls.
// Rank = cn - 2*dot via 3-pass hi/lo bf16 MFMA; gap<=TAU rows -> np-bit-exact
// block rescan. absmax 0.0 lineage R8-R10.

typedef __bf16 bf8 __attribute__((ext_vector_type(8)));
typedef float  f4  __attribute__((ext_vector_type(4)));

#define Dz     64
#define HWz    4096
#define Nz     131072
#define QSIZE  ((size_t)Nz * Dz)
#define PSTR   128       // zT row stride (floats) during staging phase
#define CROW   76        // split-cb row stride (ushorts) = 152B = 38 dwords
#define PLANE  4864      // ushorts per plane (64*76)
#define TILEU  9728      // ushorts per tile (hi+lo)
#define TILEB  19456     // bytes per tile = 19 * 1024
#define NCALL  19        // 1KB wave-calls per tile
#define TAU    4e-3f

#define MFMA(A, B, C) __builtin_amdgcn_mfma_f32_16x16x32_bf16(A, B, C, 0, 0, 0)

#define DECL8(P) float P##0, P##1, P##2, P##3, P##4, P##5, P##6, P##7;
#define DECI8(P) int   P##0, P##1, P##2, P##3, P##4, P##5, P##6, P##7;

// best/second update: second computed from OLD best (order matters).
#define UPDR(ACCE, B, K, S)                                            \
    {   const float vv = __builtin_fmaf(ACCE, -2.0f, cnv);             \
        S = fminf(S, fmaxf(B, vv));                                    \
        K = (vv < B) ? kcand : K;                                      \
        B = fminf(B, vv); }

#define REDR(B, K, S)                                                  \
    _Pragma("unroll")                                                  \
    for (int mm = 1; mm < 16; mm <<= 1) {                              \
        const float ob = __shfl_xor(B, mm, 64);                        \
        const int   ok = __shfl_xor(K, mm, 64);                        \
        const float os = __shfl_xor(S, mm, 64);                        \
        S = fminf(fminf(S, os), fmaxf(B, ob));                         \
        K = (ob < B) ? ok : K;                                         \
        B = fminf(B, ob); }

// ---------------- prep: split cb -> bf16 hi/lo tiles + exact cnorm ----------
__global__ __launch_bounds__(256) void vq_prep(
    const float* __restrict__ cb, unsigned short* __restrict__ cbws,
    float* __restrict__ cnws, float* __restrict__ lossp,
    unsigned int* __restrict__ donep) {
    const int f = blockIdx.x * 256 + threadIdx.x;   // 0..8191
    const int k = f >> 4, c = f & 15;
    if (f == 0) { lossp[0] = 0.0f; donep[0] = 0u; }
    const float4 v = ((const float4*)cb)[(size_t)k * 16 + c];
    unsigned short h0, h1, h2, h3, l0, l1, l2, l3;
#define S1(X, H, L)                                                    \
    { const __bf16 hh = (__bf16)(X);                                   \
      H = __builtin_bit_cast(unsigned short, hh);                      \
      L = __builtin_bit_cast(unsigned short, (__bf16)((X) - (float)hh)); }
    S1(v.x, h0, l0) S1(v.y, h1, l1) S1(v.z, h2, l2) S1(v.w, h3, l3)
#undef S1
    const int kt = k >> 6, kc = k & 63;
    unsigned short* hi = cbws + (size_t)kt * TILEU + kc * CROW + c * 4;
    *(ushort4*)hi = make_ushort4(h0, h1, h2, h3);             // 8B-aligned
    *(ushort4*)(hi + PLANE) = make_ushort4(l0, l1, l2, l3);   // 8B-aligned
    if (c == 0) {  // numpy pairwise-8 cnorm (squares round before add)
#pragma clang fp contract(off)
        const float4* row = (const float4*)(cb + (size_t)k * 64);
        float r0, r1, r2, r3, r4, r5, r6, r7;
        {
            float4 f0 = row[0], f1 = row[1];
            r0 = f0.x * f0.x; r1 = f0.y * f0.y; r2 = f0.z * f0.z; r3 = f0.w * f0.w;
            r4 = f1.x * f1.x; r5 = f1.y * f1.y; r6 = f1.z * f1.z; r7 = f1.w * f1.w;
        }
#pragma unroll
        for (int m = 1; m < 8; ++m) {
            float4 f0 = row[2 * m], f1 = row[2 * m + 1];
            r0 = r0 + f0.x * f0.x; r1 = r1 + f0.y * f0.y;
            r2 = r2 + f0.z * f0.z; r3 = r3 + f0.w * f0.w;
            r4 = r4 + f1.x * f1.x; r5 = r5 + f1.y * f1.y;
            r6 = r6 + f1.z * f1.z; r7 = r7 + f1.w * f1.w;
        }
        cnws[k] = ((r0 + r1) + (r2 + r3)) + ((r4 + r5) + (r6 + r7));
    }
}

// ---------------- main ----------------
// async global->LDS: per call, lane i moves 16B; LDS dest = base + lane*16.
#define ISSUE_TILE(KT, DSTOFF)                                          \
    {   const char* srcb = (const char*)cbws + (size_t)(KT) * TILEB;    \
        char* dstb = (char*)smem + (DSTOFF);                            \
        for (int j = w; j < NCALL; j += 4) {                            \
            __builtin_amdgcn_global_load_lds(                           \
                (const __attribute__((address_space(1))) void*)(srcb + j * 1024 + l * 16), \
                (__attribute__((address_space(3))) void*)(dstb + j * 1024), \
                16, 0, 0);                                              \
        }                                                               \
    }

__global__ __launch_bounds__(256, 3) void vq_main(
    const float* __restrict__ z, const float* __restrict__ cb,
    const unsigned short* __restrict__ cbws, const float* __restrict__ cnws,
    float* __restrict__ out, float* __restrict__ loss_accum,
    unsigned int* __restrict__ done_counter) {
    __shared__ alignas(16) unsigned char smem[2 * TILEB];  // zT phase, then cb dbuf
    __shared__ alignas(16) float cn_s[512];
    __shared__ int    idx_s[128];
    __shared__ unsigned long long flagm[2];
    __shared__ float  wredD[4];
    __shared__ int    wredK[4];
    __shared__ float  wsum[4];

    const int t  = threadIdx.x;
    const int w  = t >> 6;
    const int l  = t & 63;
    const int q  = l >> 4;
    const int m16 = l & 15;
    const int n0g = blockIdx.x * 128;
    const int b   = n0g >> 12;
    const int s0  = n0g & 4095;
    const float* zB = z + (size_t)b * (Dz * HWz);

    // ---- phase 1: stage zT (transpose buffer) + cn_s.
    float* zT = (float*)smem;
#pragma unroll
    for (int i = 0; i < 8; ++i) {
        const int flat = t + 256 * i;
        const int d = flat >> 5, c4 = flat & 31;
        float4 f = *(const float4*)(zB + (size_t)d * HWz + s0 + 4 * c4);
        *(float4*)(zT + d * PSTR + 4 * c4) = f;
    }
    if (t < 128) ((f4*)cn_s)[t] = ((const f4*)cnws)[t];
    __syncthreads();

    // ---- build A fragments (both 16-pos subtiles, hi+lo, 2 k-chunks).
    bf8 ah00, ah01, al00, al01, ah10, ah11, al10, al11;
    {
        const int pA = 32 * w + m16, pB = pA + 16;
#define BUILDA(AH, AL, P, KC)                                          \
        _Pragma("unroll")                                              \
        for (int j = 0; j < 8; ++j) {                                  \
            const float v = zT[((KC) * 32 + q * 8 + j) * PSTR + (P)];  \
            const __bf16 hh = (__bf16)v;                               \
            AH[j] = hh;                                                \
            AL[j] = (__bf16)(v - (float)hh);                           \
        }
        BUILDA(ah00, al00, pA, 0) BUILDA(ah01, al01, pA, 1)
        BUILDA(ah10, al10, pB, 0) BUILDA(ah11, al11, pB, 1)
#undef BUILDA
    }
    __syncthreads();            // zT dead; smem becomes the cb double buffer

    // ---- prime the pipeline: tiles 0 and 1.
    ISSUE_TILE(0, 0)
    ISSUE_TILE(1, TILEB)
    __syncthreads();            // vmcnt drained -> tiles 0,1 resident

    // ---- K loop: 8 tiles x 64 codes. One barrier per tile; prefetch issued
    // right after the barrier so its latency hides under the next compute.
    const float INF = __builtin_inff();
    DECL8(bd) DECI8(bk) DECL8(sd)
    bd0=INF;bd1=INF;bd2=INF;bd3=INF;bd4=INF;bd5=INF;bd6=INF;bd7=INF;
    sd0=INF;sd1=INF;sd2=INF;sd3=INF;sd4=INF;sd5=INF;sd6=INF;sd7=INF;
    bk0=0;bk1=0;bk2=0;bk3=0;bk4=0;bk5=0;bk6=0;bk7=0;

#pragma unroll 2
    for (int kt = 0; kt < 8; ++kt) {
        const unsigned short* hib = (const unsigned short*)(smem + (kt & 1) * TILEB);
        const int k0g = kt * 64;
#pragma unroll
        for (int n0 = 0; n0 < 64; n0 += 16) {
            const int nlane = n0 + m16;
            const int hoff = nlane * CROW + q * 8;
            const bf8 bh0 = *(const bf8*)(hib + hoff);
            const bf8 bh1 = *(const bf8*)(hib + hoff + 32);
            const bf8 bl0 = *(const bf8*)(hib + hoff + PLANE);
            const bf8 bl1 = *(const bf8*)(hib + hoff + PLANE + 32);
            f4 acc0 = {0.f, 0.f, 0.f, 0.f}, acc1 = {0.f, 0.f, 0.f, 0.f};
            acc0 = MFMA(ah00, bh0, acc0); acc0 = MFMA(ah01, bh1, acc0);
            acc1 = MFMA(ah10, bh0, acc1); acc1 = MFMA(ah11, bh1, acc1);
            acc0 = MFMA(al00, bh0, acc0); acc0 = MFMA(al01, bh1, acc0);
            acc1 = MFMA(al10, bh0, acc1); acc1 = MFMA(al11, bh1, acc1);
            acc0 = MFMA(ah00, bl0, acc0); acc0 = MFMA(ah01, bl1, acc0);
            acc1 = MFMA(ah10, bl0, acc1); acc1 = MFMA(ah11, bl1, acc1);
            const float cnv = cn_s[k0g + nlane];
            const int kcand = k0g + nlane;
            UPDR(acc0[0], bd0, bk0, sd0) UPDR(acc0[1], bd1, bk1, sd1)
            UPDR(acc0[2], bd2, bk2, sd2) UPDR(acc0[3], bd3, bk3, sd3)
            UPDR(acc1[0], bd4, bk4, sd4) UPDR(acc1[1], bd5, bk5, sd5)
            UPDR(acc1[2], bd6, bk6, sd6) UPDR(acc1[3], bd7, bk7, sd7)
        }
        __syncthreads();                       // everyone done reading buf[kt&1]
        if (kt + 2 < 8) ISSUE_TILE(kt + 2, (kt & 1) * TILEB)
    }

    // ---- cross-lane reduce + flag near-ties.
    REDR(bd0, bk0, sd0) REDR(bd1, bk1, sd1) REDR(bd2, bk2, sd2) REDR(bd3, bk3, sd3)
    REDR(bd4, bk4, sd4) REDR(bd5, bk5, sd5) REDR(bd6, bk6, sd6) REDR(bd7, bk7, sd7)
    if (m16 == 0) {
        const int base = 32 * w + 4 * q;
        idx_s[base + 0]      = (sd0 - bd0 <= TAU) ? -1 : bk0;
        idx_s[base + 1]      = (sd1 - bd1 <= TAU) ? -1 : bk1;
        idx_s[base + 2]      = (sd2 - bd2 <= TAU) ? -1 : bk2;
        idx_s[base + 3]      = (sd3 - bd3 <= TAU) ? -1 : bk3;
        idx_s[base + 16 + 0] = (sd4 - bd4 <= TAU) ? -1 : bk4;
        idx_s[base + 16 + 1] = (sd5 - bd5 <= TAU) ? -1 : bk5;
        idx_s[base + 16 + 2] = (sd6 - bd6 <= TAU) ? -1 : bk6;
        idx_s[base + 16 + 3] = (sd7 - bd7 <= TAU) ? -1 : bk7;
    }
    __syncthreads();

    // ---- ballot work-list of flagged rows.
    if (t < 128) {
        unsigned long long mflag = __ballot(idx_s[t] < 0);
        if (l == 0) flagm[w] = mflag;
    }
    __syncthreads();

    // ---- fallback: np-bit-exact rescan for flagged rows (z from global,
    // L2-warm broadcast reads; cb original fp32).
#pragma unroll 1
    for (int half = 0; half < 2; ++half) {
        unsigned long long m = flagm[half];      // block-uniform
        while (m) {
            const int row = (half << 6) + __builtin_ctzll(m);
            m &= m - 1;
            const float* zR = zB + s0 + row;     // zR[d*HWz] = z[d][s0+row]
            float zn;
            {   // np pairwise-8 znorm
#pragma clang fp contract(off)
                float c0, c1, c2, c3, c4, c5, c6, c7;
                c0 = zR[0*HWz]*zR[0*HWz]; c1 = zR[1*HWz]*zR[1*HWz];
                c2 = zR[2*HWz]*zR[2*HWz]; c3 = zR[3*HWz]*zR[3*HWz];
                c4 = zR[4*HWz]*zR[4*HWz]; c5 = zR[5*HWz]*zR[5*HWz];
                c6 = zR[6*HWz]*zR[6*HWz]; c7 = zR[7*HWz]*zR[7*HWz];
#pragma unroll
                for (int mi = 1; mi < 8; ++mi) {
                    float v0 = zR[(size_t)(8*mi+0)*HWz], v1 = zR[(size_t)(8*mi+1)*HWz];
                    float v2 = zR[(size_t)(8*mi+2)*HWz], v3 = zR[(size_t)(8*mi+3)*HWz];
                    float v4 = zR[(size_t)(8*mi+4)*HWz], v5 = zR[(size_t)(8*mi+5)*HWz];
                    float v6 = zR[(size_t)(8*mi+6)*HWz], v7 = zR[(size_t)(8*mi+7)*HWz];
                    c0 = c0 + v0*v0; c1 = c1 + v1*v1; c2 = c2 + v2*v2; c3 = c3 + v3*v3;
                    c4 = c4 + v4*v4; c5 = c5 + v5*v5; c6 = c6 + v6*v6; c7 = c7 + v7*v7;
                }
                zn = ((c0 + c1) + (c2 + c3)) + ((c4 + c5) + (c6 + c7));
            }
            float fbd; int fbk;
            {   // codes t and t+256, exact sequential-d chain (R5-validated)
                float dd0, dd1;
#pragma unroll
                for (int h = 0; h < 2; ++h) {
                    const int k = t + 256 * h;
                    const float4* C = (const float4*)(cb + (size_t)k * 64);
                    float a = 0.f;
#pragma unroll
                    for (int i = 0; i < 16; ++i) {
                        const float4 c4v = C[i];
                        a = __builtin_fmaf(zR[(size_t)(4*i+0)*HWz], c4v.x, a);
                        a = __builtin_fmaf(zR[(size_t)(4*i+1)*HWz], c4v.y, a);
                        a = __builtin_fmaf(zR[(size_t)(4*i+2)*HWz], c4v.z, a);
                        a = __builtin_fmaf(zR[(size_t)(4*i+3)*HWz], c4v.w, a);
                    }
                    const float dv = (zn - 2.0f * a) + cn_s[k];
                    if (h == 0) dd0 = dv; else dd1 = dv;
                }
                fbd = dd0; fbk = t;
                if (dd1 < fbd) { fbd = dd1; fbk = t + 256; }
            }
#pragma unroll
            for (int mm = 1; mm < 64; mm <<= 1) {
                const float ob = __shfl_xor(fbd, mm, 64);
                const int   ok = __shfl_xor(fbk, mm, 64);
                if (ob < fbd || (ob == fbd && ok < fbk)) { fbd = ob; fbk = ok; }
            }
            if (l == 0) { wredD[w] = fbd; wredK[w] = fbk; }
            __syncthreads();
            if (t == 0) {
                float fb = wredD[0]; int fk = wredK[0];
#pragma unroll
                for (int i = 1; i < 4; ++i) {
                    if (wredD[i] < fb || (wredD[i] == fb && wredK[i] < fk)) {
                        fb = wredD[i]; fk = wredK[i];
                    }
                }
                idx_s[row] = fk;
            }
            __syncthreads();
        }
    }

    // ---- epilogue: gather code, write q_st (NCHW coalesced), loss.
    // z re-read from global (block's 32KB slice is L2/L1-warm).
    const int p  = t & 127;
    const int d0 = (t >> 7) * 32;
    const int myidx = idx_s[p];
    const float* qrow = cb + (size_t)myidx * 64 + d0;
    const float* zE = zB + s0 + p;               // zE[d*HWz] = z[d][s0+p]
    float* oB = out + (size_t)b * (Dz * HWz) + s0 + p;
    float lsum = 0.f;
#pragma unroll
    for (int j = 0; j < 8; ++j) {
        const int d = d0 + 4 * j;
        const float4 q4 = *(const float4*)(qrow + 4 * j);
        const float y0 = zE[(size_t)(d + 0) * HWz];
        const float y1 = zE[(size_t)(d + 1) * HWz];
        const float y2 = zE[(size_t)(d + 2) * HWz];
        const float y3 = zE[(size_t)(d + 3) * HWz];
        const float e0 = y0 - q4.x, e1 = y1 - q4.y;
        const float e2 = y2 - q4.z, e3 = y3 - q4.w;
        lsum += e0 * e0; lsum += e1 * e1; lsum += e2 * e2; lsum += e3 * e3;
        oB[(size_t)(d + 0) * HWz] = y0 + (q4.x - y0);
        oB[(size_t)(d + 1) * HWz] = y1 + (q4.y - y1);
        oB[(size_t)(d + 2) * HWz] = y2 + (q4.z - y2);
        oB[(size_t)(d + 3) * HWz] = y3 + (q4.w - y3);
    }
#pragma unroll
    for (int off = 32; off > 0; off >>= 1) lsum += __shfl_down(lsum, off, 64);
    if (l == 0) wsum[w] = lsum;
    __syncthreads();
    if (t == 0) {
        float tot = (wsum[0] + wsum[1]) + (wsum[2] + wsum[3]);
        atomicAdd(loss_accum, tot);
        __threadfence();
        unsigned int ticket = atomicAdd(done_counter, 1u);
        if (ticket == gridDim.x - 1) {
            __threadfence();
            float total = atomicAdd(loss_accum, 0.0f);
            float X = total / (float)QSIZE;
            out[QSIZE] = X + 0.25f * X;
        }
    }
}

extern "C" void kernel_launch(void* const* d_in, const int* in_sizes, int n_in,
                              void* d_out, int out_size, void* d_ws, size_t ws_size,
                              hipStream_t stream) {
    const float* z  = (const float*)d_in[0];
    const float* cb = (const float*)d_in[1];
    float* out = (float*)d_out;
    // ws layout: [0:8) loss+done, [64 : 64+8*TILEB) split cb, then cnorm[512].
    float* lossp = (float*)d_ws;
    unsigned int* donep = (unsigned int*)((char*)d_ws + 4);
    unsigned short* cbws = (unsigned short*)((char*)d_ws + 64);
    float* cnws = (float*)((char*)d_ws + 64 + 8 * TILEB);
    vq_prep<<<32, 256, 0, stream>>>(cb, cbws, cnws, lossp, donep);
    vq_main<<<Nz / 128, 256, 0, stream>>>(z, cb, cbws, cnws, out, lossp, donep);
}

// Round 12
// 200.931 us; speedup vs baseline: 1.1924x; 1.1924x over previous
//
#include <hip/hip_runtime.h>

// VQ-VAE quantize: z [32,64,64,64] NCHW fp32, codebook [512,64] fp32.
// out = quantized (8388608 fp32, NCHW) ++ loss scalar. N=131072, D=64, K=512.
//
// R12: barrier-free K loop. R8/R10 (~110us) were ~85% stall: barrier-coupled
// LDS staging phases with ~8 waves/CU. The 128KB hi/lo codebook is
// L2-resident, so B-fragments are read STRAIGHT FROM GLOBAL in MFMA fragment
// order (prep writes cbf[chunk][lane][4x16B]): 4 coalesced dwordx4 per
// 16-code chunk, depth-1 ping-pong (32 VGPRs), 12 MFMA per chunk, no
// __syncthreads anywhere in the K loop. LDS holds only zT (alive through
// fallback/epilogue -- R11's global re-read blew up FETCH/WRITE) + cn.
// Rank = cn - 2*dot via 3-pass hi/lo bf16 MFMA; gap<=TAU rows -> np-bit-exact
// block rescan. Numerics verbatim from R8/R10 (absmax 0.0).

typedef __bf16 bf8 __attribute__((ext_vector_type(8)));
typedef float  f4  __attribute__((ext_vector_type(4)));

#define Dz     64
#define HWz    4096
#define Nz     131072
#define QSIZE  ((size_t)Nz * Dz)
#define PSTR   128       // zT row stride (floats)
#define CHB    4096      // bytes per 16-code fragment-ordered chunk
#define TAU    4e-3f

#define MFMA(A, B, C) __builtin_amdgcn_mfma_f32_16x16x32_bf16(A, B, C, 0, 0, 0)

#define DECL8(P) float P##0, P##1, P##2, P##3, P##4, P##5, P##6, P##7;
#define DECI8(P) int   P##0, P##1, P##2, P##3, P##4, P##5, P##6, P##7;

// best/second update: second computed from OLD best (order matters).
#define UPDR(ACCE, B, K, S)                                            \
    {   const float vv = __builtin_fmaf(ACCE, -2.0f, cnv);             \
        S = fminf(S, fmaxf(B, vv));                                    \
        K = (vv < B) ? kcand : K;                                      \
        B = fminf(B, vv); }

#define REDR(B, K, S)                                                  \
    _Pragma("unroll")                                                  \
    for (int mm = 1; mm < 16; mm <<= 1) {                              \
        const float ob = __shfl_xor(B, mm, 64);                        \
        const int   ok = __shfl_xor(K, mm, 64);                        \
        const float os = __shfl_xor(S, mm, 64);                        \
        S = fminf(fminf(S, os), fmaxf(B, ob));                         \
        K = (ob < B) ? ok : K;                                         \
        B = fminf(B, ob); }

// ---- prep: codebook -> bf16 hi/lo in MFMA B-fragment order + exact cnorm.
// cbf layout: chunk kk (16 codes), lane l = q*16+m16, 64B/lane:
//   [0:16)=hi d[q*8..), [16:32)=hi d[32+q*8..), [32:48)=lo, [48:64)=lo(+32).
__global__ __launch_bounds__(256) void vq_prep(
    const float* __restrict__ cb, unsigned short* __restrict__ cbf,
    float* __restrict__ cnws, float* __restrict__ lossp,
    unsigned int* __restrict__ donep) {
    const int f = blockIdx.x * 256 + threadIdx.x;   // 0..8191
    if (f == 0) { lossp[0] = 0.0f; donep[0] = 0u; }
    const int kk = f >> 8, lane = (f >> 2) & 63, part = f & 3;
    const int m16 = lane & 15, q = lane >> 4;
    const int k = kk * 16 + m16;
    const int dstart = (part & 1) * 32 + q * 8;
    const float4 a = *(const float4*)(cb + (size_t)k * 64 + dstart);
    const float4 b2 = *(const float4*)(cb + (size_t)k * 64 + dstart + 4);
    bf8 v;
#define CVT(X, J)                                                      \
    { const __bf16 hh = (__bf16)(X);                                   \
      v[J] = (part < 2) ? hh : (__bf16)((X) - (float)hh); }
    CVT(a.x, 0) CVT(a.y, 1) CVT(a.z, 2) CVT(a.w, 3)
    CVT(b2.x, 4) CVT(b2.y, 5) CVT(b2.z, 6) CVT(b2.w, 7)
#undef CVT
    *(bf8*)(cbf + (size_t)kk * 2048 + lane * 32 + part * 8) = v;
    if (f < 512) {  // numpy pairwise-8 cnorm (squares round before add)
#pragma clang fp contract(off)
        const float4* row = (const float4*)(cb + (size_t)f * 64);
        float r0, r1, r2, r3, r4, r5, r6, r7;
        {
            float4 f0 = row[0], f1 = row[1];
            r0 = f0.x * f0.x; r1 = f0.y * f0.y; r2 = f0.z * f0.z; r3 = f0.w * f0.w;
            r4 = f1.x * f1.x; r5 = f1.y * f1.y; r6 = f1.z * f1.z; r7 = f1.w * f1.w;
        }
#pragma unroll
        for (int m = 1; m < 8; ++m) {
            float4 f0 = row[2 * m], f1 = row[2 * m + 1];
            r0 = r0 + f0.x * f0.x; r1 = r1 + f0.y * f0.y;
            r2 = r2 + f0.z * f0.z; r3 = r3 + f0.w * f0.w;
            r4 = r4 + f1.x * f1.x; r5 = r5 + f1.y * f1.y;
            r6 = r6 + f1.z * f1.z; r7 = r7 + f1.w * f1.w;
        }
        cnws[f] = ((r0 + r1) + (r2 + r3)) + ((r4 + r5) + (r6 + r7));
    }
}

// ---------------- main ----------------
#define LOADB(B, KK)                                                   \
    {   const bf8* fp = (const bf8*)(cbfc + (size_t)(KK) * CHB) + l * 4; \
        B##h0 = fp[0]; B##h1 = fp[1]; B##l0 = fp[2]; B##l1 = fp[3]; }

#define COMPUTE(B, KK)                                                 \
    {   f4 acc0 = {0.f, 0.f, 0.f, 0.f}, acc1 = {0.f, 0.f, 0.f, 0.f};  \
        acc0 = MFMA(ah00, B##h0, acc0); acc0 = MFMA(ah01, B##h1, acc0); \
        acc1 = MFMA(ah10, B##h0, acc1); acc1 = MFMA(ah11, B##h1, acc1); \
        acc0 = MFMA(al00, B##h0, acc0); acc0 = MFMA(al01, B##h1, acc0); \
        acc1 = MFMA(al10, B##h0, acc1); acc1 = MFMA(al11, B##h1, acc1); \
        acc0 = MFMA(ah00, B##l0, acc0); acc0 = MFMA(ah01, B##l1, acc0); \
        acc1 = MFMA(ah10, B##l0, acc1); acc1 = MFMA(ah11, B##l1, acc1); \
        const int kcand = (KK) * 16 + m16;                             \
        const float cnv = cn_s[kcand];                                 \
        UPDR(acc0[0], bd0, bk0, sd0) UPDR(acc0[1], bd1, bk1, sd1)      \
        UPDR(acc0[2], bd2, bk2, sd2) UPDR(acc0[3], bd3, bk3, sd3)      \
        UPDR(acc1[0], bd4, bk4, sd4) UPDR(acc1[1], bd5, bk5, sd5)      \
        UPDR(acc1[2], bd6, bk6, sd6) UPDR(acc1[3], bd7, bk7, sd7)      \
    }

__global__ __launch_bounds__(256, 3) void vq_main(
    const float* __restrict__ z, const float* __restrict__ cb,
    const unsigned short* __restrict__ cbf, const float* __restrict__ cnws,
    float* __restrict__ out, float* __restrict__ loss_accum,
    unsigned int* __restrict__ done_counter) {
    __shared__ alignas(16) float zT[Dz * PSTR];   // 32768 B, alive to the end
    __shared__ alignas(16) float cn_s[512];
    __shared__ int    idx_s[128];
    __shared__ unsigned long long flagm[2];
    __shared__ float  wredD[4];
    __shared__ int    wredK[4];
    __shared__ float  wsum[4];

    const int t  = threadIdx.x;
    const int w  = t >> 6;
    const int l  = t & 63;
    const int q  = l >> 4;
    const int m16 = l & 15;
    const int n0g = blockIdx.x * 128;
    const int b   = n0g >> 12;
    const int s0  = n0g & 4095;
    const float* zB = z + (size_t)b * (Dz * HWz);
    const char* cbfc = (const char*)cbf;

    // ---- stage zT (2048 f4, flat) + cn_s.
#pragma unroll
    for (int i = 0; i < 8; ++i) {
        const int flat = t + 256 * i;
        const int d = flat >> 5, c4 = flat & 31;
        float4 f = *(const float4*)(zB + (size_t)d * HWz + s0 + 4 * c4);
        *(float4*)(zT + d * PSTR + 4 * c4) = f;
    }
    if (t < 128) ((f4*)cn_s)[t] = ((const f4*)cnws)[t];
    __syncthreads();

    // ---- build A fragments (both 16-pos subtiles, hi+lo, 2 k-chunks).
    bf8 ah00, ah01, al00, al01, ah10, ah11, al10, al11;
    {
        const int pA = 32 * w + m16, pB = pA + 16;
#define BUILDA(AH, AL, P, KC)                                          \
        _Pragma("unroll")                                              \
        for (int j = 0; j < 8; ++j) {                                  \
            const float v = zT[((KC) * 32 + q * 8 + j) * PSTR + (P)];  \
            const __bf16 hh = (__bf16)v;                               \
            AH[j] = hh;                                                \
            AL[j] = (__bf16)(v - (float)hh);                           \
        }
        BUILDA(ah00, al00, pA, 0) BUILDA(ah01, al01, pA, 1)
        BUILDA(ah10, al10, pB, 0) BUILDA(ah11, al11, pB, 1)
#undef BUILDA
    }

    // ---- K loop: 32 chunks of 16 codes, NO BARRIERS. B-frags straight from
    // global (L2-resident, coalesced dwordx4), depth-1 ping-pong.
    const float INF = __builtin_inff();
    DECL8(bd) DECI8(bk) DECL8(sd)
    bd0=INF;bd1=INF;bd2=INF;bd3=INF;bd4=INF;bd5=INF;bd6=INF;bd7=INF;
    sd0=INF;sd1=INF;sd2=INF;sd3=INF;sd4=INF;sd5=INF;sd6=INF;sd7=INF;
    bk0=0;bk1=0;bk2=0;bk3=0;bk4=0;bk5=0;bk6=0;bk7=0;

    bf8 Ph0, Ph1, Pl0, Pl1, Qh0, Qh1, Ql0, Ql1;
    LOADB(P, 0)
#pragma unroll 1
    for (int kk = 0; kk < 32; kk += 2) {
        LOADB(Q, kk + 1)
        COMPUTE(P, kk)
        if (kk + 2 < 32) LOADB(P, kk + 2)
        COMPUTE(Q, kk + 1)
    }

    // ---- cross-lane reduce + flag near-ties.
    REDR(bd0, bk0, sd0) REDR(bd1, bk1, sd1) REDR(bd2, bk2, sd2) REDR(bd3, bk3, sd3)
    REDR(bd4, bk4, sd4) REDR(bd5, bk5, sd5) REDR(bd6, bk6, sd6) REDR(bd7, bk7, sd7)
    if (m16 == 0) {
        const int base = 32 * w + 4 * q;
        idx_s[base + 0]      = (sd0 - bd0 <= TAU) ? -1 : bk0;
        idx_s[base + 1]      = (sd1 - bd1 <= TAU) ? -1 : bk1;
        idx_s[base + 2]      = (sd2 - bd2 <= TAU) ? -1 : bk2;
        idx_s[base + 3]      = (sd3 - bd3 <= TAU) ? -1 : bk3;
        idx_s[base + 16 + 0] = (sd4 - bd4 <= TAU) ? -1 : bk4;
        idx_s[base + 16 + 1] = (sd5 - bd5 <= TAU) ? -1 : bk5;
        idx_s[base + 16 + 2] = (sd6 - bd6 <= TAU) ? -1 : bk6;
        idx_s[base + 16 + 3] = (sd7 - bd7 <= TAU) ? -1 : bk7;
    }
    __syncthreads();

    // ---- ballot work-list of flagged rows.
    if (t < 128) {
        unsigned long long mflag = __ballot(idx_s[t] < 0);
        if (l == 0) flagm[w] = mflag;
    }
    __syncthreads();

    // ---- fallback: np-bit-exact rescan for flagged rows only (z from LDS).
#pragma unroll 1
    for (int half = 0; half < 2; ++half) {
        unsigned long long m = flagm[half];      // block-uniform
        while (m) {
            const int row = (half << 6) + __builtin_ctzll(m);
            m &= m - 1;
            float zn;
            {   // np pairwise-8 znorm (broadcast LDS reads)
#pragma clang fp contract(off)
                float c0, c1, c2, c3, c4, c5, c6, c7;
                c0 = zT[0*PSTR+row]*zT[0*PSTR+row]; c1 = zT[1*PSTR+row]*zT[1*PSTR+row];
                c2 = zT[2*PSTR+row]*zT[2*PSTR+row]; c3 = zT[3*PSTR+row]*zT[3*PSTR+row];
                c4 = zT[4*PSTR+row]*zT[4*PSTR+row]; c5 = zT[5*PSTR+row]*zT[5*PSTR+row];
                c6 = zT[6*PSTR+row]*zT[6*PSTR+row]; c7 = zT[7*PSTR+row]*zT[7*PSTR+row];
#pragma unroll
                for (int mi = 1; mi < 8; ++mi) {
                    float v0 = zT[(8*mi+0)*PSTR+row], v1 = zT[(8*mi+1)*PSTR+row];
                    float v2 = zT[(8*mi+2)*PSTR+row], v3 = zT[(8*mi+3)*PSTR+row];
                    float v4 = zT[(8*mi+4)*PSTR+row], v5 = zT[(8*mi+5)*PSTR+row];
                    float v6 = zT[(8*mi+6)*PSTR+row], v7 = zT[(8*mi+7)*PSTR+row];
                    c0 = c0 + v0*v0; c1 = c1 + v1*v1; c2 = c2 + v2*v2; c3 = c3 + v3*v3;
                    c4 = c4 + v4*v4; c5 = c5 + v5*v5; c6 = c6 + v6*v6; c7 = c7 + v7*v7;
                }
                zn = ((c0 + c1) + (c2 + c3)) + ((c4 + c5) + (c6 + c7));
            }
            float fbd; int fbk;
            {   // codes t and t+256, exact sequential-d chain (R5-validated)
                float dd0, dd1;
#pragma unroll
                for (int h = 0; h < 2; ++h) {
                    const int k = t + 256 * h;
                    const float4* C = (const float4*)(cb + (size_t)k * 64);
                    float a = 0.f;
#pragma unroll
                    for (int i = 0; i < 16; ++i) {
                        const float4 c4v = C[i];
                        a = __builtin_fmaf(zT[(4*i+0)*PSTR+row], c4v.x, a);
                        a = __builtin_fmaf(zT[(4*i+1)*PSTR+row], c4v.y, a);
                        a = __builtin_fmaf(zT[(4*i+2)*PSTR+row], c4v.z, a);
                        a = __builtin_fmaf(zT[(4*i+3)*PSTR+row], c4v.w, a);
                    }
                    const float dv = (zn - 2.0f * a) + cn_s[k];
                    if (h == 0) dd0 = dv; else dd1 = dv;
                }
                fbd = dd0; fbk = t;
                if (dd1 < fbd) { fbd = dd1; fbk = t + 256; }
            }
#pragma unroll
            for (int mm = 1; mm < 64; mm <<= 1) {
                const float ob = __shfl_xor(fbd, mm, 64);
                const int   ok = __shfl_xor(fbk, mm, 64);
                if (ob < fbd || (ob == fbd && ok < fbk)) { fbd = ob; fbk = ok; }
            }
            if (l == 0) { wredD[w] = fbd; wredK[w] = fbk; }
            __syncthreads();
            if (t == 0) {
                float fb = wredD[0]; int fk = wredK[0];
#pragma unroll
                for (int i = 1; i < 4; ++i) {
                    if (wredD[i] < fb || (wredD[i] == fb && wredK[i] < fk)) {
                        fb = wredD[i]; fk = wredK[i];
                    }
                }
                idx_s[row] = fk;
            }
            __syncthreads();
        }
    }

    // ---- epilogue: gather code, write q_st (NCHW coalesced), loss (z from LDS).
    const int p  = t & 127;
    const int d0 = (t >> 7) * 32;
    const int myidx = idx_s[p];
    const float* qrow = cb + (size_t)myidx * 64 + d0;
    float* oB = out + (size_t)b * (Dz * HWz) + s0 + p;
    float lsum = 0.f;
#pragma unroll
    for (int j = 0; j < 8; ++j) {
        const int d = d0 + 4 * j;
        const float4 q4 = *(const float4*)(qrow + 4 * j);
        const float y0 = zT[(d + 0) * PSTR + p];
        const float y1 = zT[(d + 1) * PSTR + p];
        const float y2 = zT[(d + 2) * PSTR + p];
        const float y3 = zT[(d + 3) * PSTR + p];
        const float e0 = y0 - q4.x, e1 = y1 - q4.y;
        const float e2 = y2 - q4.z, e3 = y3 - q4.w;
        lsum += e0 * e0; lsum += e1 * e1; lsum += e2 * e2; lsum += e3 * e3;
        oB[(size_t)(d + 0) * HWz] = y0 + (q4.x - y0);
        oB[(size_t)(d + 1) * HWz] = y1 + (q4.y - y1);
        oB[(size_t)(d + 2) * HWz] = y2 + (q4.z - y2);
        oB[(size_t)(d + 3) * HWz] = y3 + (q4.w - y3);
    }
#pragma unroll
    for (int off = 32; off > 0; off >>= 1) lsum += __shfl_down(lsum, off, 64);
    if (l == 0) wsum[w] = lsum;
    __syncthreads();
    if (t == 0) {
        float tot = (wsum[0] + wsum[1]) + (wsum[2] + wsum[3]);
        atomicAdd(loss_accum, tot);
        __threadfence();
        unsigned int ticket = atomicAdd(done_counter, 1u);
        if (ticket == gridDim.x - 1) {
            __threadfence();
            float total = atomicAdd(loss_accum, 0.0f);
            float X = total / (float)QSIZE;
            out[QSIZE] = X + 0.25f * X;
        }
    }
}

extern "C" void kernel_launch(void* const* d_in, const int* in_sizes, int n_in,
                              void* d_out, int out_size, void* d_ws, size_t ws_size,
                              hipStream_t stream) {
    const float* z  = (const float*)d_in[0];
    const float* cb = (const float*)d_in[1];
    float* out = (float*)d_out;
    // ws: [0:8) loss+done, [64 : 64+131072) cbf (frag-ordered), then cn[512].
    float* lossp = (float*)d_ws;
    unsigned int* donep = (unsigned int*)((char*)d_ws + 4);
    unsigned short* cbf = (unsigned short*)((char*)d_ws + 64);
    float* cnws = (float*)((char*)d_ws + 64 + 32 * CHB);
    vq_prep<<<32, 256, 0, stream>>>(cb, cbf, cnws, lossp, donep);
    vq_main<<<Nz / 128, 256, 0, stream>>>(z, cb, cbf, cnws, out, lossp, donep);
}

// Round 13
// 176.107 us; speedup vs baseline: 1.3605x; 1.1410x over previous
//
#include <hip/hip_runtime.h>

// VQ-VAE quantize: z [32,64,64,64] NCHW fp32, codebook [512,64] fp32.
// out = quantized (8388608 fp32, NCHW) ++ loss scalar. N=131072, D=64, K=512.
//
// R13 = R12 with the B-fragment buffer transposed to PART-MAJOR:
// cbf[chunk][part][lane][16B]. R12's lane-major layout gave every
// global_load_dwordx4 a 64B inter-lane stride (64-line gather per instr,
// 4x the L1 request count -> the observed 80% stall at 130us). Part-major
// makes each of the 4 loads per 16-code chunk one contiguous, coalesced
// 1KB transaction. Also launch_bounds(256,4): all 1024 blocks co-resident.
// Everything else verbatim from R12 (absmax 0.0 lineage): barrier-free
// K-loop, rank = cn - 2*dot via 3-pass hi/lo bf16 MFMA, gap<=TAU rows ->
// np-bit-exact block rescan, zT alive in LDS through fallback/epilogue.

typedef __bf16 bf8 __attribute__((ext_vector_type(8)));
typedef float  f4  __attribute__((ext_vector_type(4)));

#define Dz     64
#define HWz    4096
#define Nz     131072
#define QSIZE  ((size_t)Nz * Dz)
#define PSTR   128       // zT row stride (floats)
#define CHB    4096      // bytes per 16-code fragment-ordered chunk
#define TAU    4e-3f

#define MFMA(A, B, C) __builtin_amdgcn_mfma_f32_16x16x32_bf16(A, B, C, 0, 0, 0)

#define DECL8(P) float P##0, P##1, P##2, P##3, P##4, P##5, P##6, P##7;
#define DECI8(P) int   P##0, P##1, P##2, P##3, P##4, P##5, P##6, P##7;

// best/second update: second computed from OLD best (order matters).
#define UPDR(ACCE, B, K, S)                                            \
    {   const float vv = __builtin_fmaf(ACCE, -2.0f, cnv);             \
        S = fminf(S, fmaxf(B, vv));                                    \
        K = (vv < B) ? kcand : K;                                      \
        B = fminf(B, vv); }

#define REDR(B, K, S)                                                  \
    _Pragma("unroll")                                                  \
    for (int mm = 1; mm < 16; mm <<= 1) {                              \
        const float ob = __shfl_xor(B, mm, 64);                        \
        const int   ok = __shfl_xor(K, mm, 64);                        \
        const float os = __shfl_xor(S, mm, 64);                        \
        S = fminf(fminf(S, os), fmaxf(B, ob));                         \
        K = (ob < B) ? ok : K;                                         \
        B = fminf(B, ob); }

// ---- prep: codebook -> bf16 hi/lo in PART-MAJOR MFMA B-fragment order +
// exact cnorm. chunk kk (16 codes): part p (0,1=hi d0/d32; 2,3=lo), then
// lane l = q*16+m16 holds cb[kk*16+m16][(p&1)*32 + q*8 .. +8) -> 16B.
__global__ __launch_bounds__(256) void vq_prep(
    const float* __restrict__ cb, unsigned short* __restrict__ cbf,
    float* __restrict__ cnws, float* __restrict__ lossp,
    unsigned int* __restrict__ donep) {
    const int f = blockIdx.x * 256 + threadIdx.x;   // 0..8191
    if (f == 0) { lossp[0] = 0.0f; donep[0] = 0u; }
    const int kk = f >> 8, lane = (f >> 2) & 63, part = f & 3;
    const int m16 = lane & 15, q = lane >> 4;
    const int k = kk * 16 + m16;
    const int dstart = (part & 1) * 32 + q * 8;
    const float4 a = *(const float4*)(cb + (size_t)k * 64 + dstart);
    const float4 b2 = *(const float4*)(cb + (size_t)k * 64 + dstart + 4);
    bf8 v;
#define CVT(X, J)                                                      \
    { const __bf16 hh = (__bf16)(X);                                   \
      v[J] = (part < 2) ? hh : (__bf16)((X) - (float)hh); }
    CVT(a.x, 0) CVT(a.y, 1) CVT(a.z, 2) CVT(a.w, 3)
    CVT(b2.x, 4) CVT(b2.y, 5) CVT(b2.z, 6) CVT(b2.w, 7)
#undef CVT
    // part-major: chunk*2048 + part*512 + lane*8 (ushorts)
    *(bf8*)(cbf + (size_t)kk * 2048 + part * 512 + lane * 8) = v;
    if (f < 512) {  // numpy pairwise-8 cnorm (squares round before add)
#pragma clang fp contract(off)
        const float4* row = (const float4*)(cb + (size_t)f * 64);
        float r0, r1, r2, r3, r4, r5, r6, r7;
        {
            float4 f0 = row[0], f1 = row[1];
            r0 = f0.x * f0.x; r1 = f0.y * f0.y; r2 = f0.z * f0.z; r3 = f0.w * f0.w;
            r4 = f1.x * f1.x; r5 = f1.y * f1.y; r6 = f1.z * f1.z; r7 = f1.w * f1.w;
        }
#pragma unroll
        for (int m = 1; m < 8; ++m) {
            float4 f0 = row[2 * m], f1 = row[2 * m + 1];
            r0 = r0 + f0.x * f0.x; r1 = r1 + f0.y * f0.y;
            r2 = r2 + f0.z * f0.z; r3 = r3 + f0.w * f0.w;
            r4 = r4 + f1.x * f1.x; r5 = r5 + f1.y * f1.y;
            r6 = r6 + f1.z * f1.z; r7 = r7 + f1.w * f1.w;
        }
        cnws[f] = ((r0 + r1) + (r2 + r3)) + ((r4 + r5) + (r6 + r7));
    }
}

// ---------------- main ----------------
// part-major: each load is lane-contiguous (16B/lane, 1KB/instr, coalesced).
#define LOADB(B, KK)                                                   \
    {   const char* cbase = cbfc + (size_t)(KK) * CHB + l * 16;        \
        B##h0 = *(const bf8*)(cbase);                                  \
        B##h1 = *(const bf8*)(cbase + 1024);                           \
        B##l0 = *(const bf8*)(cbase + 2048);                           \
        B##l1 = *(const bf8*)(cbase + 3072); }

#define COMPUTE(B, KK)                                                 \
    {   f4 acc0 = {0.f, 0.f, 0.f, 0.f}, acc1 = {0.f, 0.f, 0.f, 0.f};  \
        acc0 = MFMA(ah00, B##h0, acc0); acc0 = MFMA(ah01, B##h1, acc0); \
        acc1 = MFMA(ah10, B##h0, acc1); acc1 = MFMA(ah11, B##h1, acc1); \
        acc0 = MFMA(al00, B##h0, acc0); acc0 = MFMA(al01, B##h1, acc0); \
        acc1 = MFMA(al10, B##h0, acc1); acc1 = MFMA(al11, B##h1, acc1); \
        acc0 = MFMA(ah00, B##l0, acc0); acc0 = MFMA(ah01, B##l1, acc0); \
        acc1 = MFMA(ah10, B##l0, acc1); acc1 = MFMA(ah11, B##l1, acc1); \
        const int kcand = (KK) * 16 + m16;                             \
        const float cnv = cn_s[kcand];                                 \
        UPDR(acc0[0], bd0, bk0, sd0) UPDR(acc0[1], bd1, bk1, sd1)      \
        UPDR(acc0[2], bd2, bk2, sd2) UPDR(acc0[3], bd3, bk3, sd3)      \
        UPDR(acc1[0], bd4, bk4, sd4) UPDR(acc1[1], bd5, bk5, sd5)      \
        UPDR(acc1[2], bd6, bk6, sd6) UPDR(acc1[3], bd7, bk7, sd7)      \
    }

__global__ __launch_bounds__(256, 4) void vq_main(
    const float* __restrict__ z, const float* __restrict__ cb,
    const unsigned short* __restrict__ cbf, const float* __restrict__ cnws,
    float* __restrict__ out, float* __restrict__ loss_accum,
    unsigned int* __restrict__ done_counter) {
    __shared__ alignas(16) float zT[Dz * PSTR];   // 32768 B, alive to the end
    __shared__ alignas(16) float cn_s[512];
    __shared__ int    idx_s[128];
    __shared__ unsigned long long flagm[2];
    __shared__ float  wredD[4];
    __shared__ int    wredK[4];
    __shared__ float  wsum[4];

    const int t  = threadIdx.x;
    const int w  = t >> 6;
    const int l  = t & 63;
    const int q  = l >> 4;
    const int m16 = l & 15;
    const int n0g = blockIdx.x * 128;
    const int b   = n0g >> 12;
    const int s0  = n0g & 4095;
    const float* zB = z + (size_t)b * (Dz * HWz);
    const char* cbfc = (const char*)cbf;

    // ---- stage zT (2048 f4, flat) + cn_s.
#pragma unroll
    for (int i = 0; i < 8; ++i) {
        const int flat = t + 256 * i;
        const int d = flat >> 5, c4 = flat & 31;
        float4 f = *(const float4*)(zB + (size_t)d * HWz + s0 + 4 * c4);
        *(float4*)(zT + d * PSTR + 4 * c4) = f;
    }
    if (t < 128) ((f4*)cn_s)[t] = ((const f4*)cnws)[t];
    __syncthreads();

    // ---- build A fragments (both 16-pos subtiles, hi+lo, 2 k-chunks).
    bf8 ah00, ah01, al00, al01, ah10, ah11, al10, al11;
    {
        const int pA = 32 * w + m16, pB = pA + 16;
#define BUILDA(AH, AL, P, KC)                                          \
        _Pragma("unroll")                                              \
        for (int j = 0; j < 8; ++j) {                                  \
            const float v = zT[((KC) * 32 + q * 8 + j) * PSTR + (P)];  \
            const __bf16 hh = (__bf16)v;                               \
            AH[j] = hh;                                                \
            AL[j] = (__bf16)(v - (float)hh);                           \
        }
        BUILDA(ah00, al00, pA, 0) BUILDA(ah01, al01, pA, 1)
        BUILDA(ah10, al10, pB, 0) BUILDA(ah11, al11, pB, 1)
#undef BUILDA
    }

    // ---- K loop: 32 chunks of 16 codes, NO BARRIERS. B-frags straight from
    // global (L2-resident, coalesced 1KB loads), depth-1 ping-pong.
    const float INF = __builtin_inff();
    DECL8(bd) DECI8(bk) DECL8(sd)
    bd0=INF;bd1=INF;bd2=INF;bd3=INF;bd4=INF;bd5=INF;bd6=INF;bd7=INF;
    sd0=INF;sd1=INF;sd2=INF;sd3=INF;sd4=INF;sd5=INF;sd6=INF;sd7=INF;
    bk0=0;bk1=0;bk2=0;bk3=0;bk4=0;bk5=0;bk6=0;bk7=0;

    bf8 Ph0, Ph1, Pl0, Pl1, Qh0, Qh1, Ql0, Ql1;
    LOADB(P, 0)
#pragma unroll 1
    for (int kk = 0; kk < 32; kk += 2) {
        LOADB(Q, kk + 1)
        COMPUTE(P, kk)
        if (kk + 2 < 32) LOADB(P, kk + 2)
        COMPUTE(Q, kk + 1)
    }

    // ---- cross-lane reduce + flag near-ties.
    REDR(bd0, bk0, sd0) REDR(bd1, bk1, sd1) REDR(bd2, bk2, sd2) REDR(bd3, bk3, sd3)
    REDR(bd4, bk4, sd4) REDR(bd5, bk5, sd5) REDR(bd6, bk6, sd6) REDR(bd7, bk7, sd7)
    if (m16 == 0) {
        const int base = 32 * w + 4 * q;
        idx_s[base + 0]      = (sd0 - bd0 <= TAU) ? -1 : bk0;
        idx_s[base + 1]      = (sd1 - bd1 <= TAU) ? -1 : bk1;
        idx_s[base + 2]      = (sd2 - bd2 <= TAU) ? -1 : bk2;
        idx_s[base + 3]      = (sd3 - bd3 <= TAU) ? -1 : bk3;
        idx_s[base + 16 + 0] = (sd4 - bd4 <= TAU) ? -1 : bk4;
        idx_s[base + 16 + 1] = (sd5 - bd5 <= TAU) ? -1 : bk5;
        idx_s[base + 16 + 2] = (sd6 - bd6 <= TAU) ? -1 : bk6;
        idx_s[base + 16 + 3] = (sd7 - bd7 <= TAU) ? -1 : bk7;
    }
    __syncthreads();

    // ---- ballot work-list of flagged rows.
    if (t < 128) {
        unsigned long long mflag = __ballot(idx_s[t] < 0);
        if (l == 0) flagm[w] = mflag;
    }
    __syncthreads();

    // ---- fallback: np-bit-exact rescan for flagged rows only (z from LDS).
#pragma unroll 1
    for (int half = 0; half < 2; ++half) {
        unsigned long long m = flagm[half];      // block-uniform
        while (m) {
            const int row = (half << 6) + __builtin_ctzll(m);
            m &= m - 1;
            float zn;
            {   // np pairwise-8 znorm (broadcast LDS reads)
#pragma clang fp contract(off)
                float c0, c1, c2, c3, c4, c5, c6, c7;
                c0 = zT[0*PSTR+row]*zT[0*PSTR+row]; c1 = zT[1*PSTR+row]*zT[1*PSTR+row];
                c2 = zT[2*PSTR+row]*zT[2*PSTR+row]; c3 = zT[3*PSTR+row]*zT[3*PSTR+row];
                c4 = zT[4*PSTR+row]*zT[4*PSTR+row]; c5 = zT[5*PSTR+row]*zT[5*PSTR+row];
                c6 = zT[6*PSTR+row]*zT[6*PSTR+row]; c7 = zT[7*PSTR+row]*zT[7*PSTR+row];
#pragma unroll
                for (int mi = 1; mi < 8; ++mi) {
                    float v0 = zT[(8*mi+0)*PSTR+row], v1 = zT[(8*mi+1)*PSTR+row];
                    float v2 = zT[(8*mi+2)*PSTR+row], v3 = zT[(8*mi+3)*PSTR+row];
                    float v4 = zT[(8*mi+4)*PSTR+row], v5 = zT[(8*mi+5)*PSTR+row];
                    float v6 = zT[(8*mi+6)*PSTR+row], v7 = zT[(8*mi+7)*PSTR+row];
                    c0 = c0 + v0*v0; c1 = c1 + v1*v1; c2 = c2 + v2*v2; c3 = c3 + v3*v3;
                    c4 = c4 + v4*v4; c5 = c5 + v5*v5; c6 = c6 + v6*v6; c7 = c7 + v7*v7;
                }
                zn = ((c0 + c1) + (c2 + c3)) + ((c4 + c5) + (c6 + c7));
            }
            float fbd; int fbk;
            {   // codes t and t+256, exact sequential-d chain (R5-validated)
                float dd0, dd1;
#pragma unroll
                for (int h = 0; h < 2; ++h) {
                    const int k = t + 256 * h;
                    const float4* C = (const float4*)(cb + (size_t)k * 64);
                    float a = 0.f;
#pragma unroll
                    for (int i = 0; i < 16; ++i) {
                        const float4 c4v = C[i];
                        a = __builtin_fmaf(zT[(4*i+0)*PSTR+row], c4v.x, a);
                        a = __builtin_fmaf(zT[(4*i+1)*PSTR+row], c4v.y, a);
                        a = __builtin_fmaf(zT[(4*i+2)*PSTR+row], c4v.z, a);
                        a = __builtin_fmaf(zT[(4*i+3)*PSTR+row], c4v.w, a);
                    }
                    const float dv = (zn - 2.0f * a) + cn_s[k];
                    if (h == 0) dd0 = dv; else dd1 = dv;
                }
                fbd = dd0; fbk = t;
                if (dd1 < fbd) { fbd = dd1; fbk = t + 256; }
            }
#pragma unroll
            for (int mm = 1; mm < 64; mm <<= 1) {
                const float ob = __shfl_xor(fbd, mm, 64);
                const int   ok = __shfl_xor(fbk, mm, 64);
                if (ob < fbd || (ob == fbd && ok < fbk)) { fbd = ob; fbk = ok; }
            }
            if (l == 0) { wredD[w] = fbd; wredK[w] = fbk; }
            __syncthreads();
            if (t == 0) {
                float fb = wredD[0]; int fk = wredK[0];
#pragma unroll
                for (int i = 1; i < 4; ++i) {
                    if (wredD[i] < fb || (wredD[i] == fb && wredK[i] < fk)) {
                        fb = wredD[i]; fk = wredK[i];
                    }
                }
                idx_s[row] = fk;
            }
            __syncthreads();
        }
    }

    // ---- epilogue: gather code, write q_st (NCHW coalesced), loss (z from LDS).
    const int p  = t & 127;
    const int d0 = (t >> 7) * 32;
    const int myidx = idx_s[p];
    const float* qrow = cb + (size_t)myidx * 64 + d0;
    float* oB = out + (size_t)b * (Dz * HWz) + s0 + p;
    float lsum = 0.f;
#pragma unroll
    for (int j = 0; j < 8; ++j) {
        const int d = d0 + 4 * j;
        const float4 q4 = *(const float4*)(qrow + 4 * j);
        const float y0 = zT[(d + 0) * PSTR + p];
        const float y1 = zT[(d + 1) * PSTR + p];
        const float y2 = zT[(d + 2) * PSTR + p];
        const float y3 = zT[(d + 3) * PSTR + p];
        const float e0 = y0 - q4.x, e1 = y1 - q4.y;
        const float e2 = y2 - q4.z, e3 = y3 - q4.w;
        lsum += e0 * e0; lsum += e1 * e1; lsum += e2 * e2; lsum += e3 * e3;
        oB[(size_t)(d + 0) * HWz] = y0 + (q4.x - y0);
        oB[(size_t)(d + 1) * HWz] = y1 + (q4.y - y1);
        oB[(size_t)(d + 2) * HWz] = y2 + (q4.z - y2);
        oB[(size_t)(d + 3) * HWz] = y3 + (q4.w - y3);
    }
#pragma unroll
    for (int off = 32; off > 0; off >>= 1) lsum += __shfl_down(lsum, off, 64);
    if (l == 0) wsum[w] = lsum;
    __syncthreads();
    if (t == 0) {
        float tot = (wsum[0] + wsum[1]) + (wsum[2] + wsum[3]);
        atomicAdd(loss_accum, tot);
        __threadfence();
        unsigned int ticket = atomicAdd(done_counter, 1u);
        if (ticket == gridDim.x - 1) {
            __threadfence();
            float total = atomicAdd(loss_accum, 0.0f);
            float X = total / (float)QSIZE;
            out[QSIZE] = X + 0.25f * X;
        }
    }
}

extern "C" void kernel_launch(void* const* d_in, const int* in_sizes, int n_in,
                              void* d_out, int out_size, void* d_ws, size_t ws_size,
                              hipStream_t stream) {
    const float* z  = (const float*)d_in[0];
    const float* cb = (const float*)d_in[1];
    float* out = (float*)d_out;
    // ws: [0:8) loss+done, [64 : 64+131072) cbf (frag-ordered), then cn[512].
    float* lossp = (float*)d_ws;
    unsigned int* donep = (unsigned int*)((char*)d_ws + 4);
    unsigned short* cbf = (unsigned short*)((char*)d_ws + 64);
    float* cnws = (float*)((char*)d_ws + 64 + 32 * CHB);
    vq_prep<<<32, 256, 0, stream>>>(cb, cbf, cnws, lossp, donep);
    vq_main<<<Nz / 128, 256, 0, stream>>>(z, cb, cbf, cnws, out, lossp, donep);
}